// Round 3
// baseline (191.755 us; speedup 1.0000x reference)
//
#include <hip/hip_runtime.h>
#include <cstdint>

typedef __attribute__((ext_vector_type(8))) short bf16x8;   // 8 bf16 = 4 VGPRs
typedef __attribute__((ext_vector_type(4))) float f32x4;    // MFMA C/D
typedef __attribute__((ext_vector_type(4))) float f4;
typedef __attribute__((ext_vector_type(4))) unsigned short u16x4;
typedef unsigned short u16;

__device__ __forceinline__ u16 f2bf(float f) {
  uint32_t u = __builtin_bit_cast(uint32_t, f);
  u += 0x7fffu + ((u >> 16) & 1u);          // round-to-nearest-even
  return (u16)(u >> 16);
}

__device__ __forceinline__ void async_cp16(const void* g, void* l) {
  __builtin_amdgcn_global_load_lds(
      (const __attribute__((address_space(1))) uint32_t*)g,
      (__attribute__((address_space(3))) uint32_t*)l, 16, 0, 0);
}

// Fused: cast x|features|prototypes -> bf16 ws region, AND zero d_out
// (harness re-poisons d_out to 0xAA before every launch; gemm3 atomically
// accumulates, so out must be zeroed in-graph before gemm3 runs).
__global__ __launch_bounds__(256) void cast3_zero(
    const float* __restrict__ x, const float* __restrict__ f,
    const float* __restrict__ p, u16* __restrict__ dst,
    float* __restrict__ outz,
    int n1, int n2, int n3, int nz4) {
  int i4 = blockIdx.x * 256 + threadIdx.x;
  int nc = (n1 + n2 + n3) / 4;
  if (i4 < nc) {
    int i = i4 * 4;
    const float* src;
    int local;
    if (i < n1) { src = x; local = i; }
    else if (i < n1 + n2) { src = f; local = i - n1; }
    else { src = p; local = i - n1 - n2; }
    f4 v = *(const f4*)(src + local);
    u16x4 o;
    o.x = f2bf(v.x); o.y = f2bf(v.y); o.z = f2bf(v.z); o.w = f2bf(v.w);
    *(u16x4*)(dst + i) = o;
  } else {
    int z = i4 - nc;
    if (z < nz4) ((f4*)outz)[z] = (f4){0.f, 0.f, 0.f, 0.f};
  }
}

// ---- shared main loop: C += A(tile, MxK-rowmajor) @ B(tile, NxK-rowmajor)^T ----
// A,B pre-offset to the tile base row. 16B-chunk XOR swizzle (verified 0 bank conflicts).
template<int TM, int TN>
__device__ __forceinline__ void mainloop(
    const u16* __restrict__ A, const u16* __restrict__ B, int K,
    int kbeg, int kend, int tid, u16* lds, f32x4 (&acc)[TM / 32][TN / 32]) {
  constexpr int BK = 64;
  constexpr int WM = TM / 2, WN = TN / 2;
  constexpr int MT = TM / 32, NT = TN / 32;
  const int lane = tid & 63;
  const int wave = tid >> 6;
  const int wrow = wave >> 1, wcol = wave & 1;

  for (int k0 = kbeg; k0 < kend; k0 += BK) {
    #pragma unroll
    for (int it = 0; it < TM / 32; ++it) {
      int c = it * 256 + tid;            // chunk index = LDS position
      int row = c >> 3, pc = c & 7;
      int gc = pc ^ (row & 7);           // which global 16B chunk lands here
      async_cp16(A + (size_t)row * K + (k0 + gc * 8),
                 &lds[(it * 256 + wave * 64) * 8]);
    }
    #pragma unroll
    for (int it = 0; it < TN / 32; ++it) {
      int c = it * 256 + tid;
      int row = c >> 3, pc = c & 7;
      int gc = pc ^ (row & 7);
      async_cp16(B + (size_t)row * K + (k0 + gc * 8),
                 &lds[TM * BK + (it * 256 + wave * 64) * 8]);
    }
    __syncthreads();

    #pragma unroll
    for (int s = 0; s < 2; ++s) {
      const int h = s * 4 + (lane >> 4);
      bf16x8 afr[MT], bfr[NT];
      #pragma unroll
      for (int i = 0; i < MT; ++i) {
        int r = wrow * WM + i * 16 + (lane & 15);
        afr[i] = *(const bf16x8*)&lds[(r * 8 + (h ^ (r & 7))) * 8];
      }
      #pragma unroll
      for (int j = 0; j < NT; ++j) {
        int r = wcol * WN + j * 16 + (lane & 15);
        bfr[j] = *(const bf16x8*)&lds[TM * BK + (r * 8 + (h ^ (r & 7))) * 8];
      }
      #pragma unroll
      for (int i = 0; i < MT; ++i)
        #pragma unroll
        for (int j = 0; j < NT; ++j)
          acc[i][j] = __builtin_amdgcn_mfma_f32_16x16x32_bf16(afr[i], bfr[j], acc[i][j], 0, 0, 0);
    }
    __syncthreads();
  }
}

// ---- GEMM1+GEMM2 merged: [x; proto](4608 x 1024) @ feat^T, per-block epilogue ----
// x-rows  -> Acat[row, f]=xf*relu(xf), Acat[row, 2048+f]=1-relu(xf)
// p-rows  -> Bcat[row, f]=th*c-al*(1-pres), Bcat[row, 2048+f]=-be*c
__global__ __launch_bounds__(256) void gemm12(
    const u16* __restrict__ xb, const u16* __restrict__ pb,
    const u16* __restrict__ fb, u16* __restrict__ Acat, u16* __restrict__ Bcat,
    const float* __restrict__ alpha, const float* __restrict__ beta,
    const float* __restrict__ theta) {
  constexpr int TM = 128, TN = 128, K = 1024, N = 2048;
  constexpr int WM = TM / 2, WN = TN / 2;
  constexpr int MT = TM / 32, NT = TN / 32;
  __shared__ u16 lds[(TM + TN) * 64];    // 32 KB

  const int tid = threadIdx.x;
  const int lane = tid & 63;
  const int wave = tid >> 6;
  const int wrow = wave >> 1, wcol = wave & 1;
  const int bm_all = blockIdx.x * TM;
  const int bn = blockIdx.y * TN;
  const bool is_x = bm_all < 4096;       // 4096 % 128 == 0: block is purely x or proto
  const u16* A = is_x ? xb + (size_t)bm_all * K : pb + (size_t)(bm_all - 4096) * K;
  const u16* B = fb + (size_t)bn * K;

  f32x4 acc[MT][NT] = {};
  mainloop<TM, TN>(A, B, K, 0, K, tid, lds, acc);

  float th = 0.f, al = 0.f, be = 0.f;
  if (!is_x) { th = theta[0]; al = alpha[0]; be = beta[0]; }
  u16* dst = is_x ? Acat : Bcat;
  const int rbase = is_x ? bm_all : bm_all - 4096;

  #pragma unroll
  for (int i = 0; i < MT; ++i) {
    const int gr0 = rbase + wrow * WM + i * 16 + (lane >> 4) * 4;
    #pragma unroll
    for (int j = 0; j < NT; ++j) {
      const int gc = bn + wcol * WN + j * 16 + (lane & 15);
      #pragma unroll
      for (int r = 0; r < 4; ++r) {
        float v = acc[i][j][r];
        float pres = v > 0.f ? v : 0.f;
        float o1, o2;
        if (is_x) { o1 = v * pres; o2 = 1.f - pres; }
        else { float cc = v * pres; o1 = th * cc - al * (1.f - pres); o2 = -be * cc; }
        size_t base = (size_t)(gr0 + r) * (size_t)(2 * N) + gc;
        dst[base]     = f2bf(o1);
        dst[base + N] = f2bf(o2);
      }
    }
  }
}

// ---- GEMM3 split-K: out(4096x512) += Acat @ Bcat^T over K=4096, 8 splits ----
__global__ __launch_bounds__(256) void gemm3(
    const u16* __restrict__ Acat, const u16* __restrict__ Bcat,
    float* __restrict__ out) {
  constexpr int TM = 128, TN = 128, K = 4096, N = 512, KSPLIT = 8;
  constexpr int WM = TM / 2, WN = TN / 2;
  constexpr int MT = TM / 32, NT = TN / 32;
  __shared__ u16 lds[(TM + TN) * 64];    // 32 KB

  const int tid = threadIdx.x;
  const int lane = tid & 63;
  const int wave = tid >> 6;
  const int wrow = wave >> 1, wcol = wave & 1;
  const int bm = blockIdx.x * TM;
  const int bn = blockIdx.y * TN;
  const int kbeg = blockIdx.z * (K / KSPLIT);
  const int kend = kbeg + (K / KSPLIT);

  f32x4 acc[MT][NT] = {};
  mainloop<TM, TN>(Acat + (size_t)bm * K, Bcat + (size_t)bn * K, K, kbeg, kend,
                   tid, lds, acc);

  #pragma unroll
  for (int i = 0; i < MT; ++i) {
    const int gr0 = bm + wrow * WM + i * 16 + (lane >> 4) * 4;
    #pragma unroll
    for (int j = 0; j < NT; ++j) {
      const int gc = bn + wcol * WN + j * 16 + (lane & 15);
      #pragma unroll
      for (int r = 0; r < 4; ++r)
        unsafeAtomicAdd(&out[(size_t)(gr0 + r) * N + gc], acc[i][j][r]);
    }
  }
}

extern "C" void kernel_launch(void* const* d_in, const int* in_sizes, int n_in,
                              void* d_out, int out_size, void* d_ws, size_t ws_size,
                              hipStream_t stream) {
  const float* x     = (const float*)d_in[0];
  const float* feat  = (const float*)d_in[1];
  const float* proto = (const float*)d_in[2];
  const float* alpha = (const float*)d_in[3];
  const float* beta  = (const float*)d_in[4];
  const float* theta = (const float*)d_in[5];
  float* out = (float*)d_out;

  constexpr int Bb = 4096, Ii = 1024, Pp = 512, Ff = 2048;

  char* ws = (char*)d_ws;
  size_t off = 0;
  u16* xb   = (u16*)(ws + off); off += (size_t)Bb * Ii * 2;      // 8.4 MB
  u16* fb   = (u16*)(ws + off); off += (size_t)Ff * Ii * 2;      // 4.2 MB
  u16* pb   = (u16*)(ws + off); off += (size_t)Pp * Ii * 2;      // 1.0 MB
  u16* Acat = (u16*)(ws + off); off += (size_t)Bb * 2 * Ff * 2;  // 33.6 MB
  u16* Bcat = (u16*)(ws + off);                                   // 4.2 MB (total ~51.4 MB)

  const int n1 = Bb * Ii, n2 = Ff * Ii, n3 = Pp * Ii;
  const int nz4 = Bb * Pp / 4;
  const int ntot = (n1 + n2 + n3) / 4 + nz4;
  cast3_zero<<<(ntot + 255) / 256, 256, 0, stream>>>(
      x, feat, proto, xb, out, n1, n2, n3, nz4);

  // merged GEMM1+GEMM2: M=4608 (36 row-tiles of 128), N=2048 (16 col-tiles of 128)
  gemm12<<<dim3(36, 16), 256, 0, stream>>>(xb, pb, fb, Acat, Bcat, alpha, beta, theta);

  // GEMM3: 4096x512, K=4096 split 8 ways -> 1024 blocks, atomic accumulate
  gemm3<<<dim3(Bb / 128, Pp / 128, 8), 256, 0, stream>>>(Acat, Bcat, out);
}

// Round 4
// 154.977 us; speedup vs baseline: 1.2373x; 1.2373x over previous
//
#include <hip/hip_runtime.h>
#include <cstdint>

typedef __attribute__((ext_vector_type(8))) short bf16x8;   // 8 bf16 = 4 VGPRs
typedef __attribute__((ext_vector_type(4))) float f32x4;    // MFMA C/D
typedef __attribute__((ext_vector_type(4))) float f4;
typedef __attribute__((ext_vector_type(4))) unsigned short u16x4;
typedef __attribute__((ext_vector_type(8))) unsigned short u16x8;
typedef unsigned short u16;

__device__ __forceinline__ u16 f2bf(float f) {
  uint32_t u = __builtin_bit_cast(uint32_t, f);
  u += 0x7fffu + ((u >> 16) & 1u);          // round-to-nearest-even
  return (u16)(u >> 16);
}

__device__ __forceinline__ void async_cp16(const void* g, void* l) {
  __builtin_amdgcn_global_load_lds(
      (const __attribute__((address_space(1))) uint32_t*)g,
      (__attribute__((address_space(3))) uint32_t*)l, 16, 0, 0);
}

// cast x | features | prototypes -> contiguous bf16 region in ws
__global__ __launch_bounds__(256) void cast3(
    const float* __restrict__ x, const float* __restrict__ f,
    const float* __restrict__ p, u16* __restrict__ dst,
    int n1, int n2, int n3) {
  int i = (blockIdx.x * 256 + threadIdx.x) * 4;
  const float* src;
  int local;
  if (i < n1) { src = x; local = i; }
  else if (i < n1 + n2) { src = f; local = i - n1; }
  else if (i < n1 + n2 + n3) { src = p; local = i - n1 - n2; }
  else return;
  f4 v = *(const f4*)(src + local);
  u16x4 o;
  o.x = f2bf(v.x); o.y = f2bf(v.y); o.z = f2bf(v.z); o.w = f2bf(v.w);
  *(u16x4*)(dst + i) = o;
}

// ---- shared main loop: C += A(tile, MxK-rowmajor) @ B(tile, NxK-rowmajor)^T ----
// A,B pre-offset to the tile base row. 16B-chunk XOR swizzle (verified 0 bank conflicts).
template<int TM, int TN>
__device__ __forceinline__ void mainloop(
    const u16* __restrict__ A, const u16* __restrict__ B, int K,
    int kbeg, int kend, int tid, u16* lds, f32x4 (&acc)[TM / 32][TN / 32]) {
  constexpr int BK = 64;
  constexpr int WM = TM / 2, WN = TN / 2;
  constexpr int MT = TM / 32, NT = TN / 32;
  const int lane = tid & 63;
  const int wave = tid >> 6;
  const int wrow = wave >> 1, wcol = wave & 1;

  for (int k0 = kbeg; k0 < kend; k0 += BK) {
    #pragma unroll
    for (int it = 0; it < TM / 32; ++it) {
      int c = it * 256 + tid;            // chunk index = LDS position
      int row = c >> 3, pc = c & 7;
      int gc = pc ^ (row & 7);           // which global 16B chunk lands here
      async_cp16(A + (size_t)row * K + (k0 + gc * 8),
                 &lds[(it * 256 + wave * 64) * 8]);
    }
    #pragma unroll
    for (int it = 0; it < TN / 32; ++it) {
      int c = it * 256 + tid;
      int row = c >> 3, pc = c & 7;
      int gc = pc ^ (row & 7);
      async_cp16(B + (size_t)row * K + (k0 + gc * 8),
                 &lds[TM * BK + (it * 256 + wave * 64) * 8]);
    }
    __syncthreads();

    #pragma unroll
    for (int s = 0; s < 2; ++s) {
      const int h = s * 4 + (lane >> 4);
      bf16x8 afr[MT], bfr[NT];
      #pragma unroll
      for (int i = 0; i < MT; ++i) {
        int r = wrow * WM + i * 16 + (lane & 15);
        afr[i] = *(const bf16x8*)&lds[(r * 8 + (h ^ (r & 7))) * 8];
      }
      #pragma unroll
      for (int j = 0; j < NT; ++j) {
        int r = wcol * WN + j * 16 + (lane & 15);
        bfr[j] = *(const bf16x8*)&lds[TM * BK + (r * 8 + (h ^ (r & 7))) * 8];
      }
      #pragma unroll
      for (int i = 0; i < MT; ++i)
        #pragma unroll
        for (int j = 0; j < NT; ++j)
          acc[i][j] = __builtin_amdgcn_mfma_f32_16x16x32_bf16(afr[i], bfr[j], acc[i][j], 0, 0, 0);
    }
    __syncthreads();
  }
}

// ---- GEMM1+GEMM2 merged: [x; proto](4608 x 1024) @ feat^T ----
// x-rows  -> Acat[row, f]=xf*relu(xf), Acat[row, 2048+f]=1-relu(xf)
// p-rows  -> Bcat[row, f]=th*c-al*(1-pres), Bcat[row, 2048+f]=-be*c
// Epilogue: LDS transpose (stride 136 u16, 16B-aligned rows) -> 256B-coalesced
// u16x8 global stores instead of scalar 2B scatter.
__global__ __launch_bounds__(256) void gemm12(
    const u16* __restrict__ xb, const u16* __restrict__ pb,
    const u16* __restrict__ fb, u16* __restrict__ Acat, u16* __restrict__ Bcat,
    const float* __restrict__ alpha, const float* __restrict__ beta,
    const float* __restrict__ theta) {
  constexpr int TM = 128, TN = 128, K = 1024, N = 2048;
  constexpr int MT = TM / 32, NT = TN / 32;
  constexpr int TSTRIDE = 136;           // u16 elems; 272B rows = 17*16B aligned
  __shared__ u16 lds[TM * TSTRIDE];      // 34816 B; mainloop uses first 32768 B

  const int tid = threadIdx.x;
  const int lane = tid & 63;
  const int wave = tid >> 6;
  const int wrow = wave >> 1, wcol = wave & 1;
  const int bm_all = blockIdx.x * TM;
  const int bn = blockIdx.y * TN;
  const bool is_x = bm_all < 4096;       // 4096 % 128 == 0: block purely x or proto
  const u16* A = is_x ? xb + (size_t)bm_all * K : pb + (size_t)(bm_all - 4096) * K;
  const u16* B = fb + (size_t)bn * K;

  f32x4 acc[MT][NT] = {};
  mainloop<TM, TN>(A, B, K, 0, K, tid, lds, acc);

  float th = 0.f, al = 0.f, be = 0.f;
  if (!is_x) { th = theta[0]; al = alpha[0]; be = beta[0]; }
  u16* dst = is_x ? Acat : Bcat;
  const int rowbase = is_x ? bm_all : bm_all - 4096;

  #pragma unroll
  for (int half = 0; half < 2; ++half) {
    __syncthreads();   // protect lds reuse (mainloop end / previous half's reads)
    #pragma unroll
    for (int i = 0; i < MT; ++i) {
      #pragma unroll
      for (int j = 0; j < NT; ++j) {
        const int cl = wcol * 64 + j * 16 + (lane & 15);
        #pragma unroll
        for (int r = 0; r < 4; ++r) {
          const int rl = wrow * 64 + i * 16 + (lane >> 4) * 4 + r;
          float v = acc[i][j][r];
          float pres = v > 0.f ? v : 0.f;
          float o;
          if (is_x) o = half == 0 ? v * pres : 1.f - pres;
          else {
            float cc = v * pres;
            o = half == 0 ? th * cc - al * (1.f - pres) : -be * cc;
          }
          lds[rl * TSTRIDE + cl] = f2bf(o);
        }
      }
    }
    __syncthreads();
    #pragma unroll
    for (int v = 0; v < 8; ++v) {
      const int rl = v * 16 + (tid >> 4);
      const int cl = (tid & 15) * 8;
      u16x8 vec = *(const u16x8*)&lds[rl * TSTRIDE + cl];
      *(u16x8*)&dst[(size_t)(rowbase + rl) * (2 * N) + bn + cl + half * N] = vec;
    }
  }
}

// ---- GEMM3 split-K: part[z] = Acat @ Bcat^T partial, plain coalesced stores ----
// Partials stored in thread-linear fragment order; reduce kernel re-maps.
__global__ __launch_bounds__(256) void gemm3(
    const u16* __restrict__ Acat, const u16* __restrict__ Bcat,
    float* __restrict__ part) {
  constexpr int TM = 128, TN = 128, K = 4096, KSPLIT = 4;
  constexpr int MT = TM / 32, NT = TN / 32;
  __shared__ u16 lds[(TM + TN) * 64];    // 32 KB

  const int tid = threadIdx.x;
  const int bm = blockIdx.x * TM;
  const int bn = blockIdx.y * TN;
  const int kbeg = blockIdx.z * (K / KSPLIT);
  const int kend = kbeg + (K / KSPLIT);

  f32x4 acc[MT][NT] = {};
  mainloop<TM, TN>(Acat + (size_t)bm * K, Bcat + (size_t)bn * K, K, kbeg, kend,
                   tid, lds, acc);

  // tileId in [0,128): 32 M-tiles x 4 N-tiles
  const size_t pbase =
      ((size_t)blockIdx.z * 128 + blockIdx.y * 32 + blockIdx.x) * 16384;
  #pragma unroll
  for (int i = 0; i < MT; ++i)
    #pragma unroll
    for (int j = 0; j < NT; ++j)
      *(f4*)&part[pbase + (i * 4 + j) * 1024 + tid * 4] = acc[i][j];
}

// ---- reduce partials over z, scatter to out (same thread mapping as gemm3) ----
__global__ __launch_bounds__(256) void reduce4(
    const float* __restrict__ part, float* __restrict__ out) {
  constexpr int N = 512;
  const int tid = threadIdx.x;
  const int lane = tid & 63;
  const int wave = tid >> 6;
  const int wrow = wave >> 1, wcol = wave & 1;
  const int tileId = blockIdx.x;           // 0..127
  const int bm = (tileId & 31) * 128;
  const int bn = (tileId >> 5) * 128;

  #pragma unroll
  for (int s = 0; s < 16; ++s) {
    f4 v = {0.f, 0.f, 0.f, 0.f};
    #pragma unroll
    for (int z = 0; z < 4; ++z)
      v += *(const f4*)&part[((size_t)z * 128 + tileId) * 16384 + s * 1024 + tid * 4];
    const int i = s >> 2, j = s & 3;
    const int gr0 = bm + wrow * 64 + i * 16 + (lane >> 4) * 4;
    const int gc = bn + wcol * 64 + j * 16 + (lane & 15);
    out[(size_t)(gr0 + 0) * N + gc] = v.x;
    out[(size_t)(gr0 + 1) * N + gc] = v.y;
    out[(size_t)(gr0 + 2) * N + gc] = v.z;
    out[(size_t)(gr0 + 3) * N + gc] = v.w;
  }
}

extern "C" void kernel_launch(void* const* d_in, const int* in_sizes, int n_in,
                              void* d_out, int out_size, void* d_ws, size_t ws_size,
                              hipStream_t stream) {
  const float* x     = (const float*)d_in[0];
  const float* feat  = (const float*)d_in[1];
  const float* proto = (const float*)d_in[2];
  const float* alpha = (const float*)d_in[3];
  const float* beta  = (const float*)d_in[4];
  const float* theta = (const float*)d_in[5];
  float* out = (float*)d_out;

  constexpr int Bb = 4096, Ii = 1024, Pp = 512, Ff = 2048;

  // ws layout: region0 [0, 33.5MB) serves cast outputs (consumed by gemm12),
  // then is reused for gemm3's fp32 partials (written after gemm12 is done).
  char* ws = (char*)d_ws;
  u16* xb    = (u16*)ws;                              // 8.4 MB
  u16* fb    = xb + (size_t)Bb * Ii;                  // 4.2 MB
  u16* pb    = fb + (size_t)Ff * Ii;                  // 1.0 MB
  float* part = (float*)ws;                           // 33.5 MB (aliases casts)
  size_t r0 = (size_t)4 * 128 * 16384 * 4;            // 33.55 MB
  u16* Acat = (u16*)(ws + r0);                        // 33.6 MB
  u16* Bcat = Acat + (size_t)Bb * 2 * Ff;             // 4.2 MB  (total ~71.3 MB)

  const int n1 = Bb * Ii, n2 = Ff * Ii, n3 = Pp * Ii;
  cast3<<<((n1 + n2 + n3) / 4 + 255) / 256, 256, 0, stream>>>(
      x, feat, proto, xb, n1, n2, n3);

  // merged GEMM1+GEMM2: M=4608 (36 row-tiles of 128), N=2048 (16 col-tiles of 128)
  gemm12<<<dim3(36, 16), 256, 0, stream>>>(xb, pb, fb, Acat, Bcat, alpha, beta, theta);

  // GEMM3: 4096x512, K=4096 split 4 ways -> 512 blocks, partials to ws
  gemm3<<<dim3(Bb / 128, Pp / 128, 4), 256, 0, stream>>>(Acat, Bcat, part);

  // reduce z=0..3 -> out
  reduce4<<<128, 256, 0, stream>>>(part, out);
}

// Round 5
// 149.722 us; speedup vs baseline: 1.2807x; 1.0351x over previous
//
#include <hip/hip_runtime.h>
#include <cstdint>

typedef __attribute__((ext_vector_type(8))) short bf16x8;   // 8 bf16 = 4 VGPRs
typedef __attribute__((ext_vector_type(4))) float f32x4;    // MFMA C/D
typedef __attribute__((ext_vector_type(4))) float f4;
typedef __attribute__((ext_vector_type(4))) unsigned short u16x4;
typedef __attribute__((ext_vector_type(8))) unsigned short u16x8;
typedef unsigned short u16;

__device__ __forceinline__ u16 f2bf(float f) {
  uint32_t u = __builtin_bit_cast(uint32_t, f);
  u += 0x7fffu + ((u >> 16) & 1u);          // round-to-nearest-even
  return (u16)(u >> 16);
}

__device__ __forceinline__ void async_cp16(const void* g, void* l) {
  __builtin_amdgcn_global_load_lds(
      (const __attribute__((address_space(1))) uint32_t*)g,
      (__attribute__((address_space(3))) uint32_t*)l, 16, 0, 0);
}

// cast x | features | prototypes -> contiguous bf16 region in ws
__global__ __launch_bounds__(256) void cast3(
    const float* __restrict__ x, const float* __restrict__ f,
    const float* __restrict__ p, u16* __restrict__ dst,
    int n1, int n2, int n3) {
  int i = (blockIdx.x * 256 + threadIdx.x) * 4;
  const float* src;
  int local;
  if (i < n1) { src = x; local = i; }
  else if (i < n1 + n2) { src = f; local = i - n1; }
  else if (i < n1 + n2 + n3) { src = p; local = i - n1 - n2; }
  else return;
  f4 v = *(const f4*)(src + local);
  u16x4 o;
  o.x = f2bf(v.x); o.y = f2bf(v.y); o.z = f2bf(v.z); o.w = f2bf(v.w);
  *(u16x4*)(dst + i) = o;
}

// ---- shared main loop: C += A(tile, MxK-rowmajor) @ B(tile, NxK-rowmajor)^T ----
// A,B pre-offset to the tile base row. 16B-chunk XOR swizzle (verified 0 bank conflicts).
template<int TM, int TN>
__device__ __forceinline__ void mainloop(
    const u16* __restrict__ A, const u16* __restrict__ B, int K,
    int kbeg, int kend, int tid, u16* lds, f32x4 (&acc)[TM / 32][TN / 32]) {
  constexpr int BK = 64;
  constexpr int WM = TM / 2, WN = TN / 2;
  constexpr int MT = TM / 32, NT = TN / 32;
  const int lane = tid & 63;
  const int wave = tid >> 6;
  const int wrow = wave >> 1, wcol = wave & 1;

  for (int k0 = kbeg; k0 < kend; k0 += BK) {
    #pragma unroll
    for (int it = 0; it < TM / 32; ++it) {
      int c = it * 256 + tid;            // chunk index = LDS position
      int row = c >> 3, pc = c & 7;
      int gc = pc ^ (row & 7);           // which global 16B chunk lands here
      async_cp16(A + (size_t)row * K + (k0 + gc * 8),
                 &lds[(it * 256 + wave * 64) * 8]);
    }
    #pragma unroll
    for (int it = 0; it < TN / 32; ++it) {
      int c = it * 256 + tid;
      int row = c >> 3, pc = c & 7;
      int gc = pc ^ (row & 7);
      async_cp16(B + (size_t)row * K + (k0 + gc * 8),
                 &lds[TM * BK + (it * 256 + wave * 64) * 8]);
    }
    __syncthreads();

    #pragma unroll
    for (int s = 0; s < 2; ++s) {
      const int h = s * 4 + (lane >> 4);
      bf16x8 afr[MT], bfr[NT];
      #pragma unroll
      for (int i = 0; i < MT; ++i) {
        int r = wrow * WM + i * 16 + (lane & 15);
        afr[i] = *(const bf16x8*)&lds[(r * 8 + (h ^ (r & 7))) * 8];
      }
      #pragma unroll
      for (int j = 0; j < NT; ++j) {
        int r = wcol * WN + j * 16 + (lane & 15);
        bfr[j] = *(const bf16x8*)&lds[TM * BK + (r * 8 + (h ^ (r & 7))) * 8];
      }
      #pragma unroll
      for (int i = 0; i < MT; ++i)
        #pragma unroll
        for (int j = 0; j < NT; ++j)
          acc[i][j] = __builtin_amdgcn_mfma_f32_16x16x32_bf16(afr[i], bfr[j], acc[i][j], 0, 0, 0);
    }
    __syncthreads();
  }
}

// ---- GEMM1+GEMM2 merged: [x; proto](4608 x 1024) @ feat^T, tile 128x64 ----
// x-rows  -> Acat[row, f]=xf*relu(xf), Acat[row, 2048+f]=1-relu(xf)
// p-rows  -> Bcat[row, f]=th*c-al*(1-pres), Bcat[row, 2048+f]=-be*c
// Epilogue: LDS transpose (stride 72 u16, 16B-aligned rows) -> 128B-coalesced
// u16x8 global stores.
__global__ __launch_bounds__(256) void gemm12(
    const u16* __restrict__ xb, const u16* __restrict__ pb,
    const u16* __restrict__ fb, u16* __restrict__ Acat, u16* __restrict__ Bcat,
    const float* __restrict__ alpha, const float* __restrict__ beta,
    const float* __restrict__ theta) {
  constexpr int TM = 128, TN = 64, K = 1024, N = 2048;
  constexpr int MT = TM / 32, NT = TN / 32;    // 4, 2
  constexpr int TSTRIDE = 72;            // u16; 144B rows = 9*16B aligned
  __shared__ u16 lds[(TM + TN) * 64];    // 24576 B; transpose uses 128*72*2=18432 B

  const int tid = threadIdx.x;
  const int lane = tid & 63;
  const int wave = tid >> 6;
  const int wrow = wave >> 1, wcol = wave & 1;
  const int bm_all = blockIdx.x * TM;
  const int bn = blockIdx.y * TN;
  const bool is_x = bm_all < 4096;       // 4096 % 128 == 0: block purely x or proto
  const u16* A = is_x ? xb + (size_t)bm_all * K : pb + (size_t)(bm_all - 4096) * K;
  const u16* B = fb + (size_t)bn * K;

  f32x4 acc[MT][NT] = {};
  mainloop<TM, TN>(A, B, K, 0, K, tid, lds, acc);

  float th = 0.f, al = 0.f, be = 0.f;
  if (!is_x) { th = theta[0]; al = alpha[0]; be = beta[0]; }
  u16* dst = is_x ? Acat : Bcat;
  const int rowbase = is_x ? bm_all : bm_all - 4096;

  #pragma unroll
  for (int half = 0; half < 2; ++half) {
    __syncthreads();   // protect lds reuse (mainloop end / previous half's reads)
    #pragma unroll
    for (int i = 0; i < MT; ++i) {
      #pragma unroll
      for (int j = 0; j < NT; ++j) {
        const int cl = wcol * 32 + j * 16 + (lane & 15);
        #pragma unroll
        for (int r = 0; r < 4; ++r) {
          const int rl = wrow * 64 + i * 16 + (lane >> 4) * 4 + r;
          float v = acc[i][j][r];
          float pres = v > 0.f ? v : 0.f;
          float o;
          if (is_x) o = half == 0 ? v * pres : 1.f - pres;
          else {
            float cc = v * pres;
            o = half == 0 ? th * cc - al * (1.f - pres) : -be * cc;
          }
          lds[rl * TSTRIDE + cl] = f2bf(o);
        }
      }
    }
    __syncthreads();
    #pragma unroll
    for (int v = 0; v < 4; ++v) {
      const int rl = v * 32 + (tid >> 3);
      const int cl = (tid & 7) * 8;
      u16x8 vec = *(const u16x8*)&lds[rl * TSTRIDE + cl];
      *(u16x8*)&dst[(size_t)(rowbase + rl) * (2 * N) + bn + cl + half * N] = vec;
    }
  }
}

// ---- GEMM3 split-K: part[z] = Acat @ Bcat^T partial, tile 128x64, KSPLIT=4 ----
// Partials stored in thread-linear fragment order; reduce kernel re-maps.
__global__ __launch_bounds__(256) void gemm3(
    const u16* __restrict__ Acat, const u16* __restrict__ Bcat,
    float* __restrict__ part) {
  constexpr int TM = 128, TN = 64, K = 4096, KSPLIT = 4;
  constexpr int MT = TM / 32, NT = TN / 32;    // 4, 2
  __shared__ u16 lds[(TM + TN) * 64];    // 24576 B

  const int tid = threadIdx.x;
  const int bm = blockIdx.x * TM;
  const int bn = blockIdx.y * TN;
  const int kbeg = blockIdx.z * (K / KSPLIT);
  const int kend = kbeg + (K / KSPLIT);

  f32x4 acc[MT][NT] = {};
  mainloop<TM, TN>(Acat + (size_t)bm * K, Bcat + (size_t)bn * K, K, kbeg, kend,
                   tid, lds, acc);

  // tile linear id: z * 256 + by * 32 + bx; per-tile 8192 floats (32 KB)
  const size_t pbase =
      ((size_t)blockIdx.z * 256 + blockIdx.y * 32 + blockIdx.x) * 8192;
  #pragma unroll
  for (int i = 0; i < MT; ++i)
    #pragma unroll
    for (int j = 0; j < NT; ++j)
      *(f4*)&part[pbase + (i * NT + j) * 1024 + tid * 4] = acc[i][j];
}

// ---- reduce partials over z, scatter to out (same thread mapping as gemm3) ----
__global__ __launch_bounds__(256) void reduce4(
    const float* __restrict__ part, float* __restrict__ out) {
  constexpr int N = 512;
  const int tid = threadIdx.x;
  const int lane = tid & 63;
  const int wave = tid >> 6;
  const int wrow = wave >> 1, wcol = wave & 1;
  const int tileId = blockIdx.x;           // 0..255 = by*32+bx
  const int bm = (tileId & 31) * 128;
  const int bn = (tileId >> 5) * 64;

  #pragma unroll
  for (int s = 0; s < 8; ++s) {
    f4 v = {0.f, 0.f, 0.f, 0.f};
    #pragma unroll
    for (int z = 0; z < 4; ++z)
      v += *(const f4*)&part[((size_t)z * 256 + tileId) * 8192 + s * 1024 + tid * 4];
    const int i = s >> 1, j = s & 1;
    const int gr0 = bm + wrow * 64 + i * 16 + (lane >> 4) * 4;
    const int gc = bn + wcol * 32 + j * 16 + (lane & 15);
    out[(size_t)(gr0 + 0) * N + gc] = v.x;
    out[(size_t)(gr0 + 1) * N + gc] = v.y;
    out[(size_t)(gr0 + 2) * N + gc] = v.z;
    out[(size_t)(gr0 + 3) * N + gc] = v.w;
  }
}

extern "C" void kernel_launch(void* const* d_in, const int* in_sizes, int n_in,
                              void* d_out, int out_size, void* d_ws, size_t ws_size,
                              hipStream_t stream) {
  const float* x     = (const float*)d_in[0];
  const float* feat  = (const float*)d_in[1];
  const float* proto = (const float*)d_in[2];
  const float* alpha = (const float*)d_in[3];
  const float* beta  = (const float*)d_in[4];
  const float* theta = (const float*)d_in[5];
  float* out = (float*)d_out;

  constexpr int Bb = 4096, Ii = 1024, Pp = 512, Ff = 2048;

  // ws layout: region0 [0, 33.5MB) serves cast outputs (consumed by gemm12),
  // then is reused for gemm3's fp32 partials (written after gemm12 is done).
  char* ws = (char*)d_ws;
  u16* xb    = (u16*)ws;                              // 8.4 MB
  u16* fb    = xb + (size_t)Bb * Ii;                  // 4.2 MB
  u16* pb    = fb + (size_t)Ff * Ii;                  // 1.0 MB
  float* part = (float*)ws;                           // 33.5 MB (aliases casts)
  size_t r0 = (size_t)4 * 256 * 8192 * 4;             // 33.55 MB
  u16* Acat = (u16*)(ws + r0);                        // 33.6 MB
  u16* Bcat = Acat + (size_t)Bb * 2 * Ff;             // 4.2 MB  (total ~71.3 MB)

  const int n1 = Bb * Ii, n2 = Ff * Ii, n3 = Pp * Ii;
  cast3<<<((n1 + n2 + n3) / 4 + 255) / 256, 256, 0, stream>>>(
      x, feat, proto, xb, n1, n2, n3);

  // merged GEMM1+GEMM2: M=4608 (36 row-tiles of 128), N=2048 (32 col-tiles of 64)
  gemm12<<<dim3(36, 32), 256, 0, stream>>>(xb, pb, fb, Acat, Bcat, alpha, beta, theta);

  // GEMM3: 4096x512, K=4096 split 4 ways -> 1024 blocks, partials to ws
  gemm3<<<dim3(Bb / 128, Pp / 64, 4), 256, 0, stream>>>(Acat, Bcat, part);

  // reduce z=0..3 -> out
  reduce4<<<256, 256, 0, stream>>>(part, out);
}